// Round 5
// baseline (2665.477 us; speedup 1.0000x reference)
//
#include <hip/hip_runtime.h>

// varletNetworks on MI355X — round 7: cut gather volume algebraically.
// Round-6 counters: compute_sacc 334us top, FETCH 968MB, VALUBusy 11% —
// pure gather kernel, W_l not cache-resident. Two reductions via CSR:
//  1) compute_sacc -> node-centric i-side walk: wn streamed in regs, only
//     wj gathered (2.05GB -> 1.02GB logical), Sacc rows written scattered.
//  2) edge_pass1 -> stats_walk: S = sum_n (di-dj) W[n] (stream, no gather);
//     Q = sum_n (di+dj) W[n]^2 - 2*sum_e wi.wj (cross-term = i-side walk,
//     512MB -> 256MB logical/layer).
// Everything else unchanged from round 6 (ws-safe layout, Wb/R in out_xe).

#define HSTEP 0.1f
#define TVEPS 1e-3f

typedef __attribute__((ext_vector_type(8))) short short8v;
typedef __attribute__((ext_vector_type(4))) float f32x4;

__device__ inline float4 f4z() { return make_float4(0.f, 0.f, 0.f, 0.f); }

__device__ inline unsigned short f2bf(float x) {
  unsigned u = __float_as_uint(x);
  unsigned r = (u + 0x7fffu + ((u >> 16) & 1u)) >> 16;
  return (unsigned short)r;
}
__device__ inline float bf2f(unsigned short h) {
  return __uint_as_float(((unsigned)h) << 16);
}

// ---------------------------------------------------------------------------
// Packing layout (per 128x128 matrix, ushorts):
//   chunk ks = k>>5 (4 chunks of 8192: hi [0,4096), lo [4096,8192))
//   within: (o>>4)*512 + lane*8 + (k&7), lane = (o&15) + 16*((k>>3)&3)
// ---------------------------------------------------------------------------
__global__ __launch_bounds__(256) void pack6(const float* __restrict__ KNopen,
                                             const float* __restrict__ KEopen,
                                             const float* __restrict__ KN,
                                             unsigned short* __restrict__ dst) {
  const int idx = blockIdx.x * 256 + threadIdx.x;  // 16384 per matrix
  const int m = blockIdx.y;                        // 6 matrices
  const int o = idx >> 7, k = idx & 127;
  const float* src;
  if (m == 0) src = KNopen;
  else if (m == 1) src = KEopen;
  else src = KN + (m - 2) * 16384;
  const float val = src[o * 128 + k];
  const unsigned short hi = f2bf(val);
  const unsigned short lo = f2bf(val - bf2f(hi));
  const int lane = (o & 15) + 16 * ((k >> 3) & 3);
  const int base =
      m * 32768 + (k >> 5) * 8192 + (o >> 4) * 512 + lane * 8 + (k & 7);
  dst[base] = hi;
  dst[base + 4096] = lo;
}

// prep_close_w: pack M1 = KNclose@KEopen (p=0) and Kc = KNclose (p=1).
__global__ __launch_bounds__(256) void prep_close_w(
    const float* __restrict__ KNclose, const float* __restrict__ KEopen,
    unsigned short* __restrict__ Apack) {
  const int idx = blockIdx.x * 256 + threadIdx.x;  // 32768
  const int p = idx >> 14, ok = idx & 16383;
  const int o = ok >> 7, k = ok & 127;
  float val;
  if (p == 0) {
    float s = 0.f;
    for (int m = 0; m < 128; ++m)
      s = fmaf(KNclose[o * 128 + m], KEopen[m * 128 + k], s);
    val = s;
  } else {
    val = KNclose[o * 128 + k];
  }
  const unsigned short hi = f2bf(val);
  const unsigned short lo = f2bf(val - bf2f(hi));
  const int chunk = p * 4 + (k >> 5);
  const int lane = (o & 15) + 16 * ((k >> 3) & 3);
  const int base = chunk * 8192 + (o >> 4) * 512 + lane * 8 + (k & 7);
  Apack[base] = hi;
  Apack[base + 4096] = lo;
}

// ---------------------------------------------------------------------------
// gemm_e_mfma: X [128,N] channel-major; Y[e][o] = sum_k K[o][k]X[k][e],
// stored [N,128].
// ---------------------------------------------------------------------------
__global__ __launch_bounds__(256, 2) void gemm_e_mfma(
    const float* __restrict__ X, const unsigned short* __restrict__ Wp,
    const int N, float* __restrict__ Yt) {
  __shared__ float4 Asf[1024];
  const int tid = threadIdx.x;
  const int l = tid & 63, w = tid >> 6;
  const int er = l & 15, kg = l >> 4;
  const long e0 = (long)blockIdx.x * 128;

  f32x4 acc[8][2];
#pragma unroll
  for (int of = 0; of < 8; ++of)
#pragma unroll
    for (int f = 0; f < 2; ++f) acc[of][f] = (f32x4){0.f, 0.f, 0.f, 0.f};

  long e_f[2];
  bool ev[2];
#pragma unroll
  for (int f = 0; f < 2; ++f) {
    long e = e0 + 32 * w + 16 * f + er;
    ev[f] = (e < N);
    e_f[f] = ev[f] ? e : (long)(N - 1);
  }

  const short8v* Ap = (const short8v*)Asf;

  for (int ks = 0; ks < 4; ++ks) {
    const float4* src = (const float4*)Wp + ks * 1024;
    __syncthreads();
    Asf[tid] = src[tid];
    Asf[tid + 256] = src[tid + 256];
    Asf[tid + 512] = src[tid + 512];
    Asf[tid + 768] = src[tid + 768];
    __syncthreads();

    short8v bh[2], bl[2];
#pragma unroll
    for (int f = 0; f < 2; ++f) {
      const float* col = X + e_f[f];
      const int kbase = 32 * ks + 8 * kg;
      float xv[8];
#pragma unroll
      for (int j = 0; j < 8; ++j) xv[j] = col[(long)(kbase + j) * N];
#pragma unroll
      for (int j = 0; j < 8; ++j) {
        const unsigned short h = f2bf(xv[j]);
        const unsigned short lo = f2bf(xv[j] - bf2f(h));
        bh[f][j] = (short)h;
        bl[f][j] = (short)lo;
      }
    }

#pragma unroll
    for (int of = 0; of < 8; ++of) {
      const short8v ah = Ap[of * 64 + l];
      const short8v al = Ap[512 + of * 64 + l];
#pragma unroll
      for (int f = 0; f < 2; ++f) {
        acc[of][f] =
            __builtin_amdgcn_mfma_f32_16x16x32_bf16(ah, bh[f], acc[of][f], 0, 0, 0);
        acc[of][f] =
            __builtin_amdgcn_mfma_f32_16x16x32_bf16(ah, bl[f], acc[of][f], 0, 0, 0);
        acc[of][f] =
            __builtin_amdgcn_mfma_f32_16x16x32_bf16(al, bh[f], acc[of][f], 0, 0, 0);
      }
    }
  }

#pragma unroll
  for (int of = 0; of < 8; ++of) {
#pragma unroll
    for (int f = 0; f < 2; ++f) {
      if (!ev[f]) continue;
      *(f32x4*)&Yt[e_f[f] * 128 + of * 16 + 4 * kg] = acc[of][f];
    }
  }
}

// ---------------------------------------------------------------------------
// gemm_n_mfma: X [N,128] row-major; Y[n][o] = sum_k X[n][k]K[o][k].
// MODE 0: store [N,128]. MODE 2: store [128,N].
// ---------------------------------------------------------------------------
template <int MODE>
__global__ __launch_bounds__(256, 2) void gemm_n_mfma(
    const float* __restrict__ X, const unsigned short* __restrict__ Wp,
    const int N, float* __restrict__ Y) {
  __shared__ float4 Asf[1024];
  const int tid = threadIdx.x;
  const int l = tid & 63, w = tid >> 6;
  const int er = l & 15, kg = l >> 4;
  const long n0 = (long)blockIdx.x * 128;

  f32x4 acc[8][2];
#pragma unroll
  for (int of = 0; of < 8; ++of)
#pragma unroll
    for (int f = 0; f < 2; ++f) acc[of][f] = (f32x4){0.f, 0.f, 0.f, 0.f};

  long n_f[2];
  bool nv[2];
#pragma unroll
  for (int f = 0; f < 2; ++f) {
    long n = n0 + 32 * w + 16 * f + er;
    nv[f] = (n < N);
    n_f[f] = nv[f] ? n : (long)(N - 1);
  }

  const short8v* Ap = (const short8v*)Asf;

  for (int ks = 0; ks < 4; ++ks) {
    const float4* src = (const float4*)Wp + ks * 1024;
    __syncthreads();
    Asf[tid] = src[tid];
    Asf[tid + 256] = src[tid + 256];
    Asf[tid + 512] = src[tid + 512];
    Asf[tid + 768] = src[tid + 768];
    __syncthreads();

    short8v bh[2], bl[2];
#pragma unroll
    for (int f = 0; f < 2; ++f) {
      const float* row = X + n_f[f] * 128 + 32 * ks + 8 * kg;
      const float4 v0 = *(const float4*)row;
      const float4 v1 = *(const float4*)(row + 4);
      float xv[8] = {v0.x, v0.y, v0.z, v0.w, v1.x, v1.y, v1.z, v1.w};
#pragma unroll
      for (int j = 0; j < 8; ++j) {
        const unsigned short h = f2bf(xv[j]);
        const unsigned short lo = f2bf(xv[j] - bf2f(h));
        bh[f][j] = (short)h;
        bl[f][j] = (short)lo;
      }
    }

#pragma unroll
    for (int of = 0; of < 8; ++of) {
      const short8v ah = Ap[of * 64 + l];
      const short8v al = Ap[512 + of * 64 + l];
#pragma unroll
      for (int f = 0; f < 2; ++f) {
        acc[of][f] =
            __builtin_amdgcn_mfma_f32_16x16x32_bf16(ah, bh[f], acc[of][f], 0, 0, 0);
        acc[of][f] =
            __builtin_amdgcn_mfma_f32_16x16x32_bf16(ah, bl[f], acc[of][f], 0, 0, 0);
        acc[of][f] =
            __builtin_amdgcn_mfma_f32_16x16x32_bf16(al, bh[f], acc[of][f], 0, 0, 0);
      }
    }
  }

  if (MODE == 0) {
#pragma unroll
    for (int of = 0; of < 8; ++of) {
#pragma unroll
      for (int f = 0; f < 2; ++f) {
        if (!nv[f]) continue;
        *(f32x4*)&Y[n_f[f] * 128 + of * 16 + 4 * kg] = acc[of][f];
      }
    }
  } else {  // MODE 2: transposed store [128,N]
#pragma unroll
    for (int of = 0; of < 8; ++of) {
#pragma unroll
      for (int f = 0; f < 2; ++f) {
        if (!nv[f]) continue;
#pragma unroll
        for (int r = 0; r < 4; ++r) {
          const long o = of * 16 + 4 * kg + r;
          Y[o * N + n_f[f]] = acc[of][f][r];
        }
      }
    }
  }
}

// ---------------------------------------------------------------------------
// gemm_n1 (fp32): X [N,128]; relu + store [N,128] + per-channel stats.
// ---------------------------------------------------------------------------
__global__ __launch_bounds__(256, 2) void gemm_n1(
    const float* __restrict__ X, const float* __restrict__ Kmat, const int N,
    float* __restrict__ Y, float* __restrict__ statS,
    float* __restrict__ statQ) {
  __shared__ float Xs[64 * 33];
  __shared__ float Ks[32 * 132];
  __shared__ float red[2 * 128 * 17];
  const int tid = threadIdx.x;
  const int ng = tid & 15, og = tid >> 4;
  const long n0 = (long)blockIdx.x * 64;

  float acc[4][8];
#pragma unroll
  for (int q = 0; q < 4; ++q)
#pragma unroll
    for (int j = 0; j < 8; ++j) acc[q][j] = 0.f;

  for (int kc = 0; kc < 128; kc += 32) {
#pragma unroll
    for (int i = 0; i < 2; ++i) {
      int f4i = tid + 256 * i;
      int n = f4i >> 3, c4 = (f4i & 7) << 2;
      long gn = n0 + n;
      float4 v = f4z();
      if (gn < N) v = *(const float4*)&X[gn * 128 + kc + c4];
      Xs[n * 33 + c4 + 0] = v.x;
      Xs[n * 33 + c4 + 1] = v.y;
      Xs[n * 33 + c4 + 2] = v.z;
      Xs[n * 33 + c4 + 3] = v.w;
    }
#pragma unroll
    for (int i = 0; i < 4; ++i) {
      int f4i = tid + 256 * i;
      int o = f4i >> 3, c4 = (f4i & 7) << 2;
      float4 v = *(const float4*)&Kmat[o * 128 + kc + c4];
      Ks[(c4 + 0) * 132 + o] = v.x;
      Ks[(c4 + 1) * 132 + o] = v.y;
      Ks[(c4 + 2) * 132 + o] = v.z;
      Ks[(c4 + 3) * 132 + o] = v.w;
    }
    __syncthreads();
#pragma unroll
    for (int kk = 0; kk < 32; ++kk) {
      float xv[4];
#pragma unroll
      for (int q = 0; q < 4; ++q) xv[q] = Xs[(4 * ng + q) * 33 + kk];
      const float4 k0 = *(const float4*)&Ks[kk * 132 + 8 * og];
      const float4 k1 = *(const float4*)&Ks[kk * 132 + 8 * og + 4];
      float kv[8] = {k0.x, k0.y, k0.z, k0.w, k1.x, k1.y, k1.z, k1.w};
#pragma unroll
      for (int q = 0; q < 4; ++q)
#pragma unroll
        for (int j = 0; j < 8; ++j) acc[q][j] = fmaf(xv[q], kv[j], acc[q][j]);
    }
    __syncthreads();
  }

#pragma unroll
  for (int q = 0; q < 4; ++q)
#pragma unroll
    for (int j = 0; j < 8; ++j) acc[q][j] = fmaxf(acc[q][j], 0.f);
#pragma unroll
  for (int q = 0; q < 4; ++q) {
    long n = n0 + 4 * ng + q;
    if (n < N) {
      *(float4*)&Y[n * 128 + 8 * og] =
          make_float4(acc[q][0], acc[q][1], acc[q][2], acc[q][3]);
      *(float4*)&Y[n * 128 + 8 * og + 4] =
          make_float4(acc[q][4], acc[q][5], acc[q][6], acc[q][7]);
    }
  }
  float* redS = red;
  float* redQ = red + 128 * 17;
#pragma unroll
  for (int j = 0; j < 8; ++j) {
    int o = 8 * og + j;
    float s = acc[0][j] + acc[1][j] + acc[2][j] + acc[3][j];
    float qq = acc[0][j] * acc[0][j] + acc[1][j] * acc[1][j] +
               acc[2][j] * acc[2][j] + acc[3][j] * acc[3][j];
    redS[o * 17 + ng] = s;
    redQ[o * 17 + ng] = qq;
  }
  __syncthreads();
  if (tid < 128) {
    float s = 0.f, qq = 0.f;
#pragma unroll
    for (int g = 0; g < 16; ++g) {
      s += redS[tid * 17 + g];
      qq += redQ[tid * 17 + g];
    }
    atomicAdd(&statS[tid], s);
    atomicAdd(&statQ[tid], qq);
  }
}

// ---------------------------------------------------------------------------
// close_edge_mfma: out[o][e] = sum_k M1[o][k]*xe[k][e] + Kc[o][k]*Sacc[e][k]
// ---------------------------------------------------------------------------
__global__ __launch_bounds__(256, 2) void close_edge_mfma(
    const float* __restrict__ xe, const float* __restrict__ Sacc,
    const unsigned short* __restrict__ Apack, const int nE,
    float* __restrict__ out) {
  __shared__ float4 Asf[1024];
  const int tid = threadIdx.x;
  const int l = tid & 63, w = tid >> 6;
  const int er = l & 15;
  const int kg = l >> 4;
  const long e0 = (long)blockIdx.x * 128;

  f32x4 acc[8][2];
#pragma unroll
  for (int of = 0; of < 8; ++of)
#pragma unroll
    for (int f = 0; f < 2; ++f) acc[of][f] = (f32x4){0.f, 0.f, 0.f, 0.f};

  long e_f[2];
  bool ev[2];
#pragma unroll
  for (int f = 0; f < 2; ++f) {
    long e = e0 + 32 * w + 16 * f + er;
    ev[f] = (e < nE);
    e_f[f] = ev[f] ? e : (long)(nE - 1);
  }

  const short8v* Ap = (const short8v*)Asf;

  for (int p = 0; p < 2; ++p) {
    for (int ks = 0; ks < 4; ++ks) {
      const float4* src = (const float4*)Apack + (p * 4 + ks) * 1024;
      __syncthreads();
      Asf[tid] = src[tid];
      Asf[tid + 256] = src[tid + 256];
      Asf[tid + 512] = src[tid + 512];
      Asf[tid + 768] = src[tid + 768];
      __syncthreads();

      short8v bh[2], bl[2];
#pragma unroll
      for (int f = 0; f < 2; ++f) {
        float xv[8];
        if (p == 0) {
          const float* col = xe + e_f[f];
          const int kbase = 32 * ks + 8 * kg;
#pragma unroll
          for (int j = 0; j < 8; ++j) xv[j] = col[(long)(kbase + j) * nE];
        } else {
          const float* row = Sacc + e_f[f] * 128 + 32 * ks + 8 * kg;
          const float4 v0 = *(const float4*)row;
          const float4 v1 = *(const float4*)(row + 4);
          xv[0] = v0.x; xv[1] = v0.y; xv[2] = v0.z; xv[3] = v0.w;
          xv[4] = v1.x; xv[5] = v1.y; xv[6] = v1.z; xv[7] = v1.w;
        }
#pragma unroll
        for (int j = 0; j < 8; ++j) {
          const unsigned short h = f2bf(xv[j]);
          const unsigned short lo = f2bf(xv[j] - bf2f(h));
          bh[f][j] = (short)h;
          bl[f][j] = (short)lo;
        }
      }

#pragma unroll
      for (int of = 0; of < 8; ++of) {
        const short8v ah = Ap[of * 64 + l];
        const short8v al = Ap[512 + of * 64 + l];
#pragma unroll
        for (int f = 0; f < 2; ++f) {
          acc[of][f] =
              __builtin_amdgcn_mfma_f32_16x16x32_bf16(ah, bh[f], acc[of][f], 0, 0, 0);
          acc[of][f] =
              __builtin_amdgcn_mfma_f32_16x16x32_bf16(ah, bl[f], acc[of][f], 0, 0, 0);
          acc[of][f] =
              __builtin_amdgcn_mfma_f32_16x16x32_bf16(al, bh[f], acc[of][f], 0, 0, 0);
        }
      }
    }
  }

#pragma unroll
  for (int of = 0; of < 8; ++of) {
#pragma unroll
    for (int f = 0; f < 2; ++f) {
      if (!ev[f]) continue;
      const long e = e_f[f];
#pragma unroll
      for (int r = 0; r < 4; ++r) {
        const long o = of * 16 + 4 * kg + r;
        out[o * nE + e] = acc[of][f][r];
      }
    }
  }
}

// ---------------------------------------------------------------------------
// CSR build. Entry = (e<<1)|sign (sign 1 => n was j). adjO = other endpoint.
// cnt accumulates total degree (di+dj); degD accumulates di-dj.
// ---------------------------------------------------------------------------
__global__ __launch_bounds__(256) void count_deg(const int* __restrict__ iInd,
                                                 const int* __restrict__ jInd,
                                                 const int nE,
                                                 int* __restrict__ cnt,
                                                 int* __restrict__ degD) {
  const int e = blockIdx.x * 256 + threadIdx.x;
  if (e >= nE) return;
  atomicAdd(&cnt[iInd[e]], 1);
  atomicAdd(&cnt[jInd[e]], 1);
  atomicAdd(&degD[iInd[e]], 1);
  atomicAdd(&degD[jInd[e]], -1);
}

__global__ __launch_bounds__(1024) void scan_rowptr(const int* __restrict__ cnt,
                                                    int* __restrict__ rp,
                                                    const int nN) {
  __shared__ int buf[1024];
  __shared__ int carry;
  const int tid = threadIdx.x;
  if (tid == 0) {
    carry = 0;
    rp[0] = 0;
  }
  __syncthreads();
  for (int base = 0; base < nN; base += 1024) {
    int idx = base + tid;
    int v = (idx < nN) ? cnt[idx] : 0;
    buf[tid] = v;
    __syncthreads();
    for (int off = 1; off < 1024; off <<= 1) {
      int t = (tid >= off) ? buf[tid - off] : 0;
      __syncthreads();
      buf[tid] += t;
      __syncthreads();
    }
    if (idx < nN) rp[idx + 1] = buf[tid] + carry;
    __syncthreads();
    if (tid == 0) carry += buf[1023];
    __syncthreads();
  }
}

__global__ __launch_bounds__(256) void fill_adj(const int* __restrict__ iInd,
                                                const int* __restrict__ jInd,
                                                const int nE,
                                                const int* __restrict__ rp,
                                                int* __restrict__ cur,
                                                int* __restrict__ adj,
                                                int* __restrict__ adjO) {
  const int e = blockIdx.x * 256 + threadIdx.x;
  if (e >= nE) return;
  const int ii = iInd[e], jj = jInd[e];
  int s1 = atomicAdd(&cur[ii], 1);
  adj[rp[ii] + s1] = (e << 1);
  adjO[rp[ii] + s1] = jj;
  int s2 = atomicAdd(&cur[jj], 1);
  adj[rp[jj] + s2] = (e << 1) | 1;
  adjO[rp[jj] + s2] = ii;
}

// ---------------------------------------------------------------------------
// div_open: Dacc[n,:] = sum_{(e,s) in adj(n)} +-E[e,:]   (E = Eopen [nE,128])
// ---------------------------------------------------------------------------
__global__ __launch_bounds__(256) void div_open(
    const float* __restrict__ E, const int* __restrict__ rp,
    const int* __restrict__ adj, float* __restrict__ Dacc, const int nN) {
  const int cg = threadIdx.x & 31, slot = threadIdx.x >> 5;
  const long n = (long)blockIdx.x * 8 + slot;
  if (n >= nN) return;
  const float4* E4 = (const float4*)E;
  float4 acc = f4z();
  const int b = rp[n], en = rp[n + 1];
  for (int k = b; k < en; ++k) {
    const int ent = adj[k];
    const long e = ent >> 1;
    const float4 v = E4[e * 32 + cg];
    if (ent & 1) {
      acc.x -= v.x; acc.y -= v.y; acc.z -= v.z; acc.w -= v.w;
    } else {
      acc.x += v.x; acc.y += v.y; acc.z += v.z; acc.w += v.w;
    }
  }
  ((float4*)Dacc)[n * 32 + cg] = acc;
}

// ---------------------------------------------------------------------------
// stats_walk (replaces edge_pass1):
//   S_c  = sum_n (di-dj)(n) W[n,c]                (stream)
//   Q2_c = sum_n (di+dj)(n) W[n,c]^2              (stream)
//   X_c  = sum_e W[i_e,c] W[j_e,c]                (i-side CSR gather walk)
// var_c = Q2_c - 2 X_c - nE*mu_c^2.  64 nodes per block (8/slot).
// ---------------------------------------------------------------------------
__global__ __launch_bounds__(256) void stats_walk(
    const float* __restrict__ W, const int* __restrict__ rp,
    const int* __restrict__ adj, const int* __restrict__ adjO,
    const int* __restrict__ degS, const int* __restrict__ degD, const int nN,
    float* __restrict__ statS, float* __restrict__ statQ2,
    float* __restrict__ statX) {
  __shared__ float4 red[3 * 256];  // 12KB
  const int tid = threadIdx.x;
  const int cg = tid & 31, slot = tid >> 5;
  const float4* W4 = (const float4*)W;
  float4 S = f4z(), Q = f4z(), X = f4z();
  const long n0 = (long)blockIdx.x * 64;
  for (int t = 0; t < 8; ++t) {
    const long n = n0 + t * 8 + slot;
    if (n >= nN) break;
    const float dD = (float)degD[n];
    const float dS = (float)degS[n];
    const float4 wn = W4[n * 32 + cg];
    S.x = fmaf(dD, wn.x, S.x);
    S.y = fmaf(dD, wn.y, S.y);
    S.z = fmaf(dD, wn.z, S.z);
    S.w = fmaf(dD, wn.w, S.w);
    Q.x = fmaf(dS * wn.x, wn.x, Q.x);
    Q.y = fmaf(dS * wn.y, wn.y, Q.y);
    Q.z = fmaf(dS * wn.z, wn.z, Q.z);
    Q.w = fmaf(dS * wn.w, wn.w, Q.w);
    const int b = rp[n], en = rp[n + 1];
    for (int k = b; k < en; ++k) {
      if (adj[k] & 1) continue;  // i-side only: each edge counted once
      const long o = adjO[k];
      const float4 wo = W4[o * 32 + cg];
      X.x = fmaf(wn.x, wo.x, X.x);
      X.y = fmaf(wn.y, wo.y, X.y);
      X.z = fmaf(wn.z, wo.z, X.z);
      X.w = fmaf(wn.w, wo.w, X.w);
    }
  }
  red[tid] = S;
  red[256 + tid] = Q;
  red[512 + tid] = X;
  __syncthreads();
  if (tid < 32) {
    float4 aS = red[tid], aQ = red[256 + tid], aX = red[512 + tid];
#pragma unroll
    for (int g = 1; g < 8; ++g) {
      const float4 bS = red[32 * g + tid];
      const float4 bQ = red[256 + 32 * g + tid];
      const float4 bX = red[512 + 32 * g + tid];
      aS.x += bS.x; aS.y += bS.y; aS.z += bS.z; aS.w += bS.w;
      aQ.x += bQ.x; aQ.y += bQ.y; aQ.z += bQ.z; aQ.w += bQ.w;
      aX.x += bX.x; aX.y += bX.y; aX.z += bX.z; aX.w += bX.w;
    }
    atomicAdd(&statS[tid * 4 + 0], aS.x);
    atomicAdd(&statS[tid * 4 + 1], aS.y);
    atomicAdd(&statS[tid * 4 + 2], aS.z);
    atomicAdd(&statS[tid * 4 + 3], aS.w);
    atomicAdd(&statQ2[tid * 4 + 0], aQ.x);
    atomicAdd(&statQ2[tid * 4 + 1], aQ.y);
    atomicAdd(&statQ2[tid * 4 + 2], aQ.z);
    atomicAdd(&statQ2[tid * 4 + 3], aQ.w);
    atomicAdd(&statX[tid * 4 + 0], aX.x);
    atomicAdd(&statX[tid * 4 + 1], aX.y);
    atomicAdd(&statX[tid * 4 + 2], aX.z);
    atomicAdd(&statX[tid * 4 + 3], aX.w);
  }
}

// ---------------------------------------------------------------------------
// div_fused: Dacc[n,:] += sum_{(e,s) in adj(n)} +- r_e, with
// r_e = H*relu((W[i_e]-W[j_e]-mu)*sig) computed on the fly.
// ---------------------------------------------------------------------------
__global__ __launch_bounds__(256) void div_fused(
    const float* __restrict__ W, const int* __restrict__ rp,
    const int* __restrict__ adj, const int* __restrict__ adjO,
    const float* __restrict__ mean, const float* __restrict__ rsig,
    float* __restrict__ Dacc, const int nN) {
  const int cg = threadIdx.x & 31, slot = threadIdx.x >> 5;
  const long n = (long)blockIdx.x * 8 + slot;
  if (n >= nN) return;
  const float4* W4 = (const float4*)W;
  const float4 mu = *(const float4*)&mean[cg * 4];
  const float4 sg = *(const float4*)&rsig[cg * 4];
  const float4 wn = W4[n * 32 + cg];
  float4 acc = ((const float4*)Dacc)[n * 32 + cg];
  const int b = rp[n], en = rp[n + 1];
  for (int k = b; k < en; ++k) {
    const float s = (adj[k] & 1) ? -1.f : 1.f;
    const long o = adjO[k];
    const float4 wo = W4[o * 32 + cg];
    const float t0 = fmaxf((s * (wn.x - wo.x) - mu.x) * sg.x, 0.f);
    const float t1 = fmaxf((s * (wn.y - wo.y) - mu.y) * sg.y, 0.f);
    const float t2 = fmaxf((s * (wn.z - wo.z) - mu.z) * sg.z, 0.f);
    const float t3 = fmaxf((s * (wn.w - wo.w) - mu.w) * sg.w, 0.f);
    const float sh = s * HSTEP;
    acc.x = fmaf(sh, t0, acc.x);
    acc.y = fmaf(sh, t1, acc.y);
    acc.z = fmaf(sh, t2, acc.z);
    acc.w = fmaf(sh, t3, acc.w);
  }
  ((float4*)Dacc)[n * 32 + cg] = acc;
}

// ---------------------------------------------------------------------------
// compute_sacc_csr: node-centric i-side walk. For node n, wn (4 layers) in
// registers; per i-edge gather wj (4 layers), write Sacc[e,:] once.
// ---------------------------------------------------------------------------
__global__ __launch_bounds__(256) void compute_sacc_csr(
    const float* __restrict__ Wb, const long lstr4, const int* __restrict__ rp,
    const int* __restrict__ adj, const int* __restrict__ adjO, const int nN,
    const float* __restrict__ meanAll, const float* __restrict__ rsigAll,
    float* __restrict__ Sacc) {
  const int cg = threadIdx.x & 31, slot = threadIdx.x >> 5;
  const long n = (long)blockIdx.x * 8 + slot;
  if (n >= nN) return;
  const float4* W4 = (const float4*)Wb;
  float4 mu[4], sg[4], wn[4];
#pragma unroll
  for (int l = 0; l < 4; ++l) {
    mu[l] = *(const float4*)&meanAll[l * 128 + cg * 4];
    sg[l] = *(const float4*)&rsigAll[l * 128 + cg * 4];
    wn[l] = W4[l * lstr4 + n * 32 + cg];
  }
  float4* S4 = (float4*)Sacc;
  const int b = rp[n], en = rp[n + 1];
  for (int k = b; k < en; ++k) {
    const int ent = adj[k];
    if (ent & 1) continue;  // i-side only; every edge has exactly one
    const long e = ent >> 1;
    const long j = adjO[k];
    float4 acc = f4z();
#pragma unroll
    for (int l = 0; l < 4; ++l) {
      const float4 wj = W4[l * lstr4 + j * 32 + cg];
      acc.x += HSTEP * fmaxf(((wn[l].x - wj.x) - mu[l].x) * sg[l].x, 0.f);
      acc.y += HSTEP * fmaxf(((wn[l].y - wj.y) - mu[l].y) * sg[l].y, 0.f);
      acc.z += HSTEP * fmaxf(((wn[l].z - wj.z) - mu[l].z) * sg[l].z, 0.f);
      acc.w += HSTEP * fmaxf(((wn[l].w - wj.w) - mu[l].w) * sg[l].w, 0.f);
    }
    S4[e * 32 + cg] = acc;
  }
}

// ---------------------------------------------------------------------------
__global__ void fin_statsE(const float* __restrict__ S,
                           const float* __restrict__ Q2,
                           const float* __restrict__ X, const float cnt,
                           float* __restrict__ mean, float* __restrict__ rsig) {
  const int c = threadIdx.x;  // 128
  const float mu = S[c] / cnt;
  const float q = Q2[c] - 2.f * X[c];
  const float var = q - cnt * mu * mu;
  mean[c] = mu;
  rsig[c] = rsqrtf(var + TVEPS);
}

__global__ void fin_stats(const float* __restrict__ S,
                          const float* __restrict__ Q, const float cnt,
                          float* __restrict__ mean, float* __restrict__ rsig) {
  const int c = threadIdx.x;  // 128
  const float mu = S[c] / cnt;
  const float var = Q[c] - cnt * mu * mu;
  mean[c] = mu;
  rsig[c] = rsqrtf(var + TVEPS);
}

__global__ __launch_bounds__(256) void apply_node(
    const float* __restrict__ R, const float* __restrict__ mean,
    const float* __restrict__ rsig, float* __restrict__ xnt,
    const long total4) {
  const long idx = (long)blockIdx.x * 256 + threadIdx.x;
  if (idx >= total4) return;
  const int o4 = (int)(idx & 31) * 4;
  const float4 m = *(const float4*)&mean[o4];
  const float4 s = *(const float4*)&rsig[o4];
  const float4 r = ((const float4*)R)[idx];
  float4 x = ((float4*)xnt)[idx];
  x.x += HSTEP * fmaxf((r.x - m.x) * s.x, 0.f);
  x.y += HSTEP * fmaxf((r.y - m.y) * s.y, 0.f);
  x.z += HSTEP * fmaxf((r.z - m.z) * s.z, 0.f);
  x.w += HSTEP * fmaxf((r.w - m.w) * s.w, 0.f);
  ((float4*)xnt)[idx] = x;
}

// ---------------------------------------------------------------------------
extern "C" void kernel_launch(void* const* d_in, const int* in_sizes, int n_in,
                              void* d_out, int out_size, void* d_ws,
                              size_t ws_size, hipStream_t stream) {
  const float* xn = (const float*)d_in[0];
  const float* xe = (const float*)d_in[1];
  const int* iInd = (const int*)d_in[2];
  const int* jInd = (const int*)d_in[3];
  const float* KNopen = (const float*)d_in[4];
  const float* KEopen = (const float*)d_in[5];
  const float* KNclose = (const float*)d_in[6];
  const float* KN = (const float*)d_in[8];
  const float* KE = (const float*)d_in[9];

  const int nN = in_sizes[0] / 128;
  const int nE = in_sizes[2];

  float* out_xn = (float*)d_out;
  float* out_xe = (float*)d_out + (size_t)128 * nN;

  // ---- workspace (~318MB) ----
  float* ws = (float*)d_ws;
  size_t off = 0;
  float* Sacc = ws + off; off += (size_t)nE * 128;  // 256MB; aliases Eopen
  float* Dacc = ws + off; off += (size_t)nN * 128;
  float* xnt  = ws + off; off += (size_t)nN * 128;
  unsigned short* Apack = (unsigned short*)(ws + off); off += 32768;
  unsigned short* Wpack = (unsigned short*)(ws + off); off += 98304;
  float* stats = ws + off; off += 2048;
  // [0]S_e [128]Q2_e [256]X_e [384]S_n [512]Q_n [640]meanN [768]rsigN
  // [896+128l]meanE_l [1408+128l]rsigE_l
  float* statS = stats;         float* statQ2 = stats + 128;
  float* statX = stats + 256;
  float* statS2 = stats + 384;  float* statQn = stats + 512;
  float* meanN = stats + 640;   float* rsigN = stats + 768;
  float* meanEall = stats + 896;
  float* rsigEall = stats + 1408;
  int* rp   = (int*)(ws + off); off += (size_t)nN + 1 + 63;
  int* cnt  = (int*)(ws + off); off += nN;  // stays = di+dj (degS)
  int* cur  = (int*)(ws + off); off += nN;
  int* degD = (int*)(ws + off); off += nN;  // di-dj
  int* adj  = (int*)(ws + off); off += (size_t)2 * nE;
  int* adjO = (int*)(ws + off); off += (size_t)2 * nE;
  float* Eopen = Sacc;  // alias: Eopen dead after div_open; Sacc written last

  // ---- d_out scratch: out_xe dead until the last two dispatches ----
  float* Wb = out_xe;                          // 4 x nN*128 = 102.4MB
  float* R  = out_xe + (size_t)4 * nN * 128;   // 25.6MB

  const int gN = (nN + 63) / 64;
  const int gNm = (nN + 127) / 128;
  const int gEm = (nE + 127) / 128;
  const int gEdge = (nE + 255) / 256;
  const int gGath = (nN + 7) / 8;
  const int gStat = (nN + 63) / 64;
  const int gA = (int)(((long)nN * 32 + 255) / 256);
  const long lstr4 = (long)nN * 32;

  // ---- CSR build ----
  hipMemsetAsync(cnt, 0, (size_t)nN * sizeof(int), stream);
  hipMemsetAsync(cur, 0, (size_t)nN * sizeof(int), stream);
  hipMemsetAsync(degD, 0, (size_t)nN * sizeof(int), stream);
  count_deg<<<gEdge, 256, 0, stream>>>(iInd, jInd, nE, cnt, degD);
  scan_rowptr<<<1, 1024, 0, stream>>>(cnt, rp, nN);
  fill_adj<<<gEdge, 256, 0, stream>>>(iInd, jInd, nE, rp, cur, adj, adjO);

  // ---- weight packs ----
  pack6<<<dim3(64, 6), 256, 0, stream>>>(KNopen, KEopen, KN, Wpack);
  prep_close_w<<<128, 256, 0, stream>>>(KNclose, KEopen, Apack);

  // ---- open ----
  gemm_e_mfma<<<gNm, 256, 0, stream>>>(xn, Wpack, nN, xnt);
  gemm_e_mfma<<<gEm, 256, 0, stream>>>(xe, Wpack + 32768, nE, Eopen);
  div_open<<<gGath, 256, 0, stream>>>(Eopen, rp, adj, Dacc, nN);

  // ---- layers ----
  for (int layer = 0; layer < 4; ++layer) {
    float* Wl = Wb + (size_t)layer * nN * 128;
    float* meanE = meanEall + 128 * layer;
    float* rsigE = rsigEall + 128 * layer;
    hipMemsetAsync(stats, 0, 640 * sizeof(float), stream);
    gemm_n_mfma<0><<<gNm, 256, 0, stream>>>(
        xnt, Wpack + (size_t)(2 + layer) * 32768, nN, Wl);
    stats_walk<<<gStat, 256, 0, stream>>>(Wl, rp, adj, adjO, cnt, degD, nN,
                                          statS, statQ2, statX);
    fin_statsE<<<1, 128, 0, stream>>>(statS, statQ2, statX, (float)nE, meanE,
                                      rsigE);
    div_fused<<<gGath, 256, 0, stream>>>(Wl, rp, adj, adjO, meanE, rsigE,
                                         Dacc, nN);
    gemm_n1<<<gN, 256, 0, stream>>>(Dacc, KE + layer * 16384, nN, R, statS2,
                                    statQn);
    fin_stats<<<1, 128, 0, stream>>>(statS2, statQn, (float)nN, meanN, rsigN);
    apply_node<<<gA, 256, 0, stream>>>(R, meanN, rsigN, xnt, (long)nN * 32);
  }

  // ---- Sacc (once, node-centric) + close ----
  compute_sacc_csr<<<gGath, 256, 0, stream>>>(Wb, lstr4, rp, adj, adjO, nN,
                                              meanEall, rsigEall, Sacc);
  gemm_n_mfma<2><<<gNm, 256, 0, stream>>>(xnt, Apack + 32768, nN, out_xn);
  close_edge_mfma<<<gEm, 256, 0, stream>>>(xe, Sacc, Apack, nE, out_xe);
}